// Round 5
// baseline (876.021 us; speedup 1.0000x reference)
//
#include <hip/hip_runtime.h>
#include <hip/hip_bf16.h>
#include <cstdint>

typedef __hip_bfloat16 bf16;
typedef __hip_bfloat162 bf162;
typedef __bf16 bf16x8 __attribute__((ext_vector_type(8)));
typedef float f32x4 __attribute__((ext_vector_type(4)));

// ---------- dtype detection ----------
__global__ void detect_kernel(const unsigned short* __restrict__ xr, int* __restrict__ flag) {
  if (threadIdx.x == 0 && blockIdx.x == 0) {
    int pass = 0;
    for (int i = 0; i < 64; ++i) {
      unsigned short h = xr[2 * i];
      int e = (h >> 7) & 0xFF;
      if (e >= 110 && e <= 140) pass++;
    }
    *flag = (pass >= 32) ? 1 : 0;
  }
}

// ---------- batched weight conversion: 12 tensors in one launch ----------
struct CvtDesc {
  const void* src;
  void* dst;
  int n, fi, fo, mode;  // mode 1: transpose [fi][fo] -> bf16 [fo][fi]; mode 0: flat fp32
};
struct CvtAll { CvtDesc d[12]; };

__global__ void convert_all_kernel(CvtAll all, const int* __restrict__ flag) {
  CvtDesc dd = all.d[blockIdx.y];
  int isbf = *flag;
  for (int i = blockIdx.x * blockDim.x + threadIdx.x; i < dd.n; i += gridDim.x * blockDim.x) {
    float v = isbf ? __bfloat162float(((const bf16*)dd.src)[i]) : ((const float*)dd.src)[i];
    if (dd.mode) {
      int k = i / dd.fo, nn = i - k * dd.fo;
      ((__bf16*)dd.dst)[(size_t)nn * dd.fi + k] = (__bf16)v;
    } else {
      ((float*)dd.dst)[i] = v;
    }
  }
}

// ---------- graph preprocessing ----------

__global__ void count_kernel(const int* __restrict__ dst, int* __restrict__ deg, int E) {
  int i = blockIdx.x * blockDim.x + threadIdx.x;
  if (i < E) atomicAdd(&deg[dst[i]], 1);
}

__global__ void dinv_kernel(const int* __restrict__ deg, float* __restrict__ dinv, int n) {
  int i = blockIdx.x * blockDim.x + threadIdx.x;
  if (i < n) dinv[i] = rsqrtf((float)(deg[i] + 1));  // +1 self-loop
}

__global__ void scan_block_kernel(const int* __restrict__ counts, int* __restrict__ excl,
                                  int* __restrict__ bsum, int n) {
  __shared__ int sd[1024];
  int t = threadIdx.x;
  int i = blockIdx.x * 1024 + t;
  int v = (i < n) ? counts[i] : 0;
  sd[t] = v;
  __syncthreads();
  for (int off = 1; off < 1024; off <<= 1) {
    int x = (t >= off) ? sd[t - off] : 0;
    __syncthreads();
    sd[t] += x;
    __syncthreads();
  }
  if (i < n) excl[i] = sd[t] - v;
  if (t == 1023) bsum[blockIdx.x] = sd[1023];
}

__global__ void scan_sums_kernel(int* __restrict__ bsum, int nb, int* __restrict__ row_ptr, int n) {
  __shared__ int sd[1024];
  int t = threadIdx.x;
  int v = (t < nb) ? bsum[t] : 0;
  sd[t] = v;
  __syncthreads();
  for (int off = 1; off < 1024; off <<= 1) {
    int x = (t >= off) ? sd[t - off] : 0;
    __syncthreads();
    sd[t] += x;
    __syncthreads();
  }
  if (t < nb) bsum[t] = sd[t] - v;
  if (t == 1023) row_ptr[n] = sd[1023];
}

__global__ void scan_add_kernel(int* __restrict__ excl, const int* __restrict__ bsum, int n) {
  int i = blockIdx.x * blockDim.x + threadIdx.x;
  if (i < n) excl[i] += bsum[i >> 10];
}

__global__ void fill_kernel(const int* __restrict__ src, const int* __restrict__ dst,
                            const int* __restrict__ row_ptr, int* __restrict__ cursor,
                            int* __restrict__ col, int E) {
  int i = blockIdx.x * blockDim.x + threadIdx.x;
  if (i < E) {
    int d = dst[i];
    int pos = row_ptr[d] + atomicAdd(&cursor[d], 1);
    col[pos] = src[i];
  }
}

// ---------- async global->LDS helper (16B, literal size per guide) ----------
__device__ __forceinline__ void gload_lds16(const void* g, void* l) {
  __builtin_amdgcn_global_load_lds(
      (const __attribute__((address_space(1))) void*)g,
      (__attribute__((address_space(3))) void*)l, 16, 0, 0);
}

// ---------- MFMA GEMM (K large), m97-style LDS-staged 2-phase pipeline ----------
// Used for conv0 (K=512) only: BK=64 double-buffered LDS staging via
// global_load_lds; XOR swizzle slot^(row&7) applied as pre-swizzled GLOBAL
// source + swizzled read addr, LDS dest linear (rule #21). Wave: 64x64
// quadrant via 4x4 of 16x16x32 MFMA; C/D layout col=lane&15, row=quad*4+reg.
// For K=128 this pipeline is all overhead (NT=2) and 64KB LDS caps occupancy
// -> round-3 delta arithmetic says K=128 regressed ~8-10us each; those now
// use the reg-dbuf kernel below.

template <int K, int ADUAL>
__global__ __launch_bounds__(256) void gemm_mfma_kernel(
    const void* __restrict__ Ain, const __bf16* __restrict__ Bt,
    const float* __restrict__ bias, bf16* __restrict__ C,
    int M, const float* __restrict__ rowscale, int do_relu,
    const int* __restrict__ flag) {
  constexpr int BK = 64;        // K-elems per tile (128B rows in LDS)
  constexpr int NT = K / BK;
  __shared__ __align__(16) __bf16 As[2][128 * BK];  // 16KB per buffer
  __shared__ __align__(16) __bf16 Bs[2][128 * BK];

  const int abf = ADUAL ? flag[0] : 1;  // 1 => A is bf16
  int t = threadIdx.x;
  int wave = t >> 6, lane = t & 63;
  int l15 = lane & 15, quad = lane >> 4;
  int wm = wave >> 1, wn = wave & 1;
  int rowbase = blockIdx.x * 128;
  const __bf16* Ab = (const __bf16*)Ain;
  const float* Af = (const float*)Ain;

  // staging decomposition: thread t covers LDS row srow(+32 per inst), slot sslot
  int srow = t >> 3;       // 0..31
  int sslot = t & 7;       // 16B slot within 128B row
  int xslot = sslot ^ (srow & 7);  // pre-swizzled source slot

  int sArow[4];  // clamped global A rows for the 4 staging insts
#pragma unroll
  for (int i = 0; i < 4; ++i) {
    int r = rowbase + i * 32 + srow;
    sArow[i] = (r < M) ? r : (M - 1);  // dup loads harmless; masked at store
  }

  f32x4 acc[4][4];
#pragma unroll
  for (int mt = 0; mt < 4; ++mt)
#pragma unroll
    for (int nt = 0; nt < 4; ++nt) acc[mt][nt] = (f32x4){0.f, 0.f, 0.f, 0.f};

  auto stage = [&](int kt, int buf) {
    int kbase = kt * BK + xslot * 8;  // element offset incl. swizzled slot
    if (abf) {
#pragma unroll
      for (int i = 0; i < 4; ++i)
        gload_lds16(Ab + (size_t)sArow[i] * K + kbase, &As[buf][t * 8 + i * 2048]);
    } else {
#pragma unroll
      for (int i = 0; i < 4; ++i) {
        const float* p = Af + (size_t)sArow[i] * K + kbase;
        bf16x8 v;
#pragma unroll
        for (int j = 0; j < 8; ++j) v[j] = (__bf16)p[j];
        *(bf16x8*)&As[buf][t * 8 + i * 2048] = v;
      }
    }
#pragma unroll
    for (int i = 0; i < 4; ++i)
      gload_lds16(Bt + (size_t)(i * 32 + srow) * K + kbase, &Bs[buf][t * 8 + i * 2048]);
  };

  auto compute = [&](int buf) {
#pragma unroll
    for (int c = 0; c < 2; ++c) {  // two K=32 chunks per BK=64 tile
      bf16x8 av[4], bv[4];
#pragma unroll
      for (int mt = 0; mt < 4; ++mt) {
        int row = wm * 64 + mt * 16 + l15;
        int slot = (c * 4 + quad) ^ (row & 7);
        av[mt] = *(const bf16x8*)&As[buf][row * BK + slot * 8];
      }
#pragma unroll
      for (int nt = 0; nt < 4; ++nt) {
        int row = wn * 64 + nt * 16 + l15;
        int slot = (c * 4 + quad) ^ (row & 7);
        bv[nt] = *(const bf16x8*)&Bs[buf][row * BK + slot * 8];
      }
#pragma unroll
      for (int mt = 0; mt < 4; ++mt)
#pragma unroll
        for (int nt = 0; nt < 4; ++nt)
          acc[mt][nt] =
              __builtin_amdgcn_mfma_f32_16x16x32_bf16(av[mt], bv[nt], acc[mt][nt], 0, 0, 0);
    }
  };

  stage(0, 0);
  __syncthreads();  // drains vmcnt(0): tile 0 resident
#pragma unroll
  for (int kt = 0; kt < NT; ++kt) {
    int cur = kt & 1;
    if (kt + 1 < NT) stage(kt + 1, cur ^ 1);  // async DMA flies under compute
    compute(cur);
    __syncthreads();  // vmcnt(0)+barrier: next tile ready, cur reusable
  }

#pragma unroll
  for (int mt = 0; mt < 4; ++mt) {
    int r0 = rowbase + wm * 64 + mt * 16 + quad * 4;
#pragma unroll
    for (int nt = 0; nt < 4; ++nt) {
      int c = wn * 64 + nt * 16 + l15;
      float bs = bias[c];
#pragma unroll
      for (int i = 0; i < 4; ++i) {
        int r = r0 + i;
        if (r < M) {
          float v = acc[mt][nt][i] + bs;
          if (rowscale) v *= rowscale[r];
          if (do_relu) v = fmaxf(v, 0.f);
          C[(size_t)r * 128 + c] = __float2bfloat16(v);
        }
      }
    }
  }
}

// ---------- MFMA GEMM (K=128), register double-buffered, no LDS ----------
// Round-1 proven code, verbatim. For K=128 the whole per-wave A/B working set
// is 4 chunks; reg double-buffer + L2-resident Bt beats the LDS pipeline
// (which has NT=2 tiles and 2-blocks/CU occupancy).

template <int K, int ADUAL>
__global__ __launch_bounds__(256) void gemm_mfma_reg_kernel(
    const void* __restrict__ Ain, const __bf16* __restrict__ Bt,
    const float* __restrict__ bias, bf16* __restrict__ C,
    int M, const float* __restrict__ rowscale, int do_relu,
    const int* __restrict__ flag) {
  const int abf = ADUAL ? flag[0] : 1;  // 1 => A is bf16
  int t = threadIdx.x;
  int wave = t >> 6, lane = t & 63;
  int l15 = lane & 15, quad = lane >> 4;
  int wm = wave >> 1, wn = wave & 1;
  int rowbase = blockIdx.x * 128 + wm * 64;
  int colbase = wn * 64;
  const __bf16* Ab = (const __bf16*)Ain;
  const float* Af = (const float*)Ain;

  f32x4 acc[4][4];
#pragma unroll
  for (int mt = 0; mt < 4; ++mt)
#pragma unroll
    for (int nt = 0; nt < 4; ++nt) acc[mt][nt] = (f32x4){0.f, 0.f, 0.f, 0.f};

  int arow[4];
#pragma unroll
  for (int mt = 0; mt < 4; ++mt) {
    int r = rowbase + mt * 16 + l15;
    arow[mt] = (r < M) ? r : (M - 1);  // clamp; garbage rows masked at store
  }
  int brow[4];
#pragma unroll
  for (int nt = 0; nt < 4; ++nt) brow[nt] = colbase + nt * 16 + l15;

  bf16x8 aA[4], bA[4], aB[4], bB[4];

  auto load_chunk = [&](int kc, bf16x8 (&av)[4], bf16x8 (&bv)[4]) {
    int ko = kc + quad * 8;
    if (abf) {
#pragma unroll
      for (int mt = 0; mt < 4; ++mt)
        av[mt] = *(const bf16x8*)(Ab + (size_t)arow[mt] * K + ko);
    } else {
#pragma unroll
      for (int mt = 0; mt < 4; ++mt) {
        const float* p = Af + (size_t)arow[mt] * K + ko;
#pragma unroll
        for (int j = 0; j < 8; ++j) av[mt][j] = (__bf16)p[j];
      }
    }
#pragma unroll
    for (int nt = 0; nt < 4; ++nt)
      bv[nt] = *(const bf16x8*)(Bt + (size_t)brow[nt] * K + ko);
  };

  auto mfma16 = [&](const bf16x8 (&av)[4], const bf16x8 (&bv)[4]) {
#pragma unroll
    for (int mt = 0; mt < 4; ++mt)
#pragma unroll
      for (int nt = 0; nt < 4; ++nt)
        acc[mt][nt] =
            __builtin_amdgcn_mfma_f32_16x16x32_bf16(av[mt], bv[nt], acc[mt][nt], 0, 0, 0);
  };

  constexpr int NC = K / 32;  // 4 for K=128; always even
  load_chunk(0, aA, bA);
#pragma unroll
  for (int c = 0; c < NC; c += 2) {
    if (c + 1 < NC) load_chunk((c + 1) * 32, aB, bB);
    mfma16(aA, bA);
    if (c + 2 < NC) load_chunk((c + 2) * 32, aA, bA);
    if (c + 1 < NC) mfma16(aB, bB);
  }

#pragma unroll
  for (int mt = 0; mt < 4; ++mt) {
    int r0 = rowbase + mt * 16 + quad * 4;
#pragma unroll
    for (int nt = 0; nt < 4; ++nt) {
      int c = colbase + nt * 16 + l15;
      float bs = bias[c];
#pragma unroll
      for (int i = 0; i < 4; ++i) {
        int r = r0 + i;
        if (r < M) {
          float v = acc[mt][nt][i] + bs;
          if (rowscale) v *= rowscale[r];
          if (do_relu) v = fmaxf(v, 0.f);
          C[(size_t)r * 128 + c] = __float2bfloat16(v);
        }
      }
    }
  }
}

// ---------- gather: y[d] = relu(dinv[d]*(g[d] + sum_{s in CSR[d]} g[s])) ----------
// Latency-bound random 256B row reads from a 25.6MB buffer (mostly L3-served,
// ~600cy). Round-4 version kept only 8 rows in flight and serialized
// {col loads -> row loads} per batch. Now: 16-deep row pipeline + next
// batch's col indices prefetched WHILE current rows are in flight, breaking
// the serial col->row chain. Masked tail rows dup col[beg]'s row (L1-hot).

__global__ __launch_bounds__(256) void gather_kernel(
    const bf16* __restrict__ g, const int* __restrict__ row_ptr, const int* __restrict__ col,
    const float* __restrict__ dinv, bf16* __restrict__ y, int n) {
  int wave = threadIdx.x >> 6;
  int lane = threadIdx.x & 63;
  int node = blockIdx.x * 4 + wave;
  if (node >= n) return;
  const bf162* gp = (const bf162*)g;
  bf162 sv = gp[(size_t)node * 64 + lane];
  float ax = __bfloat162float(sv.x), ay = __bfloat162float(sv.y);
  float bx = 0.f, by = 0.f;
  int beg = row_ptr[node], end = row_ptr[node + 1];

  if (beg < end) {
    int sc[16], sn[16];
    float mc[16], mn[16];
#pragma unroll
    for (int j = 0; j < 16; ++j) {
      int ee = beg + j;
      bool ok = ee < end;
      sc[j] = col[ok ? ee : beg];
      mc[j] = ok ? 1.f : 0.f;
    }
    for (int e = beg; e < end; e += 16) {
      // issue 16 row loads (current batch)
      bf162 v[16];
#pragma unroll
      for (int j = 0; j < 16; ++j) v[j] = gp[(size_t)sc[j] * 64 + lane];
      // prefetch next batch's col indices while rows are in flight
      int e2 = e + 16;
      bool more = e2 < end;
      if (more) {
#pragma unroll
        for (int j = 0; j < 16; ++j) {
          int ee = e2 + j;
          bool ok = ee < end;
          sn[j] = col[ok ? ee : beg];
          mn[j] = ok ? 1.f : 0.f;
        }
      }
      // accumulate (4 independent chains of 8 fma)
#pragma unroll
      for (int j = 0; j < 16; j += 2) {
        ax = fmaf(mc[j], __bfloat162float(v[j].x), ax);
        ay = fmaf(mc[j], __bfloat162float(v[j].y), ay);
        bx = fmaf(mc[j + 1], __bfloat162float(v[j + 1].x), bx);
        by = fmaf(mc[j + 1], __bfloat162float(v[j + 1].y), by);
      }
      if (more) {
#pragma unroll
        for (int j = 0; j < 16; ++j) {
          sc[j] = sn[j];
          mc[j] = mn[j];
        }
      }
    }
  }
  float dv = dinv[node];
  float ox = fmaxf((ax + bx) * dv, 0.f);
  float oy = fmaxf((ay + by) * dv, 0.f);
  bf162 o;
  o.x = __float2bfloat16(ox);
  o.y = __float2bfloat16(oy);
  ((bf162*)y)[(size_t)node * 64 + lane] = o;
}

// ---------- fused FC chain: out = log_softmax(relu(relu(y@W1+b1)@W2+b2)@W3+b3) ----------
// All three FC layers are row-local -> fuse per 128-row block. LDS h-tiles
// padded to 136 elems/row (272B = 17*16B): 16B-aligned ds_read_b128,
// row-to-row bank advance 4 -> ~2-way residual aliasing (free, m136).
// 69.6 KB LDS -> 2 blocks/CU.

__global__ __launch_bounds__(256) void fc_chain_kernel(
    const bf16* __restrict__ yin, const __bf16* __restrict__ W1t,
    const float* __restrict__ b1, const __bf16* __restrict__ W2t,
    const float* __restrict__ b2, const __bf16* __restrict__ W3t,
    const float* __restrict__ b3, void* __restrict__ out, int M,
    const int* __restrict__ flag) {
  constexpr int LDH = 136;  // padded row stride in elems
  __shared__ __align__(16) __bf16 h1[128 * LDH];
  __shared__ __align__(16) __bf16 h2[128 * LDH];
  const int isbf = flag[0];
  int t = threadIdx.x;
  int wave = t >> 6, lane = t & 63;
  int l15 = lane & 15, quad = lane >> 4;
  int wm = wave >> 1, wn = wave & 1;
  int rowbase = blockIdx.x * 128;

  f32x4 acc[4][4];
  bf16x8 aA[4], bA[4], aB[4], bB[4];

  auto zacc = [&]() {
#pragma unroll
    for (int mt = 0; mt < 4; ++mt)
#pragma unroll
      for (int nt = 0; nt < 4; ++nt) acc[mt][nt] = (f32x4){0.f, 0.f, 0.f, 0.f};
  };
  auto mfma16 = [&](const bf16x8 (&av)[4], const bf16x8 (&bv)[4]) {
#pragma unroll
    for (int mt = 0; mt < 4; ++mt)
#pragma unroll
      for (int nt = 0; nt < 4; ++nt)
        acc[mt][nt] =
            __builtin_amdgcn_mfma_f32_16x16x32_bf16(av[mt], bv[nt], acc[mt][nt], 0, 0, 0);
  };

  // ---- phase 1: h1 = relu(yin @ W1t^T + b1), A from global ----
  int arow[4];
#pragma unroll
  for (int mt = 0; mt < 4; ++mt) {
    int r = rowbase + wm * 64 + mt * 16 + l15;
    arow[mt] = (r < M) ? r : (M - 1);  // clamp; dup rows never stored to out
  }
  auto ld1 = [&](int kc, bf16x8 (&av)[4], bf16x8 (&bv)[4]) {
    int ko = kc + quad * 8;
#pragma unroll
    for (int mt = 0; mt < 4; ++mt)
      av[mt] = *(const bf16x8*)(yin + (size_t)arow[mt] * 128 + ko);
#pragma unroll
    for (int nt = 0; nt < 4; ++nt)
      bv[nt] = *(const bf16x8*)(W1t + (size_t)(wn * 64 + nt * 16 + l15) * 128 + ko);
  };
  zacc();
  ld1(0, aA, bA);
  ld1(32, aB, bB);
  mfma16(aA, bA);
  ld1(64, aA, bA);
  mfma16(aB, bB);
  ld1(96, aB, bB);
  mfma16(aA, bA);
  mfma16(aB, bB);
#pragma unroll
  for (int mt = 0; mt < 4; ++mt) {
    int rl0 = wm * 64 + mt * 16 + quad * 4;
#pragma unroll
    for (int nt = 0; nt < 4; ++nt) {
      int c = wn * 64 + nt * 16 + l15;
      float bs = b1[c];
#pragma unroll
      for (int i = 0; i < 4; ++i)
        h1[(rl0 + i) * LDH + c] = (__bf16)fmaxf(acc[mt][nt][i] + bs, 0.f);
    }
  }
  __syncthreads();

  // ---- phase 2: h2 = relu(h1 @ W2t^T + b2), A from LDS ----
  auto ld2 = [&](int kc, bf16x8 (&av)[4], bf16x8 (&bv)[4]) {
    int ko = kc + quad * 8;
#pragma unroll
    for (int mt = 0; mt < 4; ++mt)
      av[mt] = *(const bf16x8*)&h1[(wm * 64 + mt * 16 + l15) * LDH + ko];
#pragma unroll
    for (int nt = 0; nt < 4; ++nt)
      bv[nt] = *(const bf16x8*)(W2t + (size_t)(wn * 64 + nt * 16 + l15) * 128 + ko);
  };
  zacc();
  ld2(0, aA, bA);
  ld2(32, aB, bB);
  mfma16(aA, bA);
  ld2(64, aA, bA);
  mfma16(aB, bB);
  ld2(96, aB, bB);
  mfma16(aA, bA);
  mfma16(aB, bB);
#pragma unroll
  for (int mt = 0; mt < 4; ++mt) {
    int rl0 = wm * 64 + mt * 16 + quad * 4;
#pragma unroll
    for (int nt = 0; nt < 4; ++nt) {
      int c = wn * 64 + nt * 16 + l15;
      float bs = b2[c];
#pragma unroll
      for (int i = 0; i < 4; ++i)
        h2[(rl0 + i) * LDH + c] = (__bf16)fmaxf(acc[mt][nt][i] + bs, 0.f);
    }
  }
  __syncthreads();

  // ---- phase 3: out = log_softmax(h2 @ W3t^T + b3), wave w -> rows w*32.. ----
  f32x4 acc3[2][4];
#pragma unroll
  for (int mt = 0; mt < 2; ++mt)
#pragma unroll
    for (int nt = 0; nt < 4; ++nt) acc3[mt][nt] = (f32x4){0.f, 0.f, 0.f, 0.f};
  bf16x8 a3A[2], a3B[2];
  auto ld3 = [&](int kc, bf16x8 (&av)[2], bf16x8 (&bv)[4]) {
    int ko = kc + quad * 8;
#pragma unroll
    for (int mt = 0; mt < 2; ++mt)
      av[mt] = *(const bf16x8*)&h2[(wave * 32 + mt * 16 + l15) * LDH + ko];
#pragma unroll
    for (int nt = 0; nt < 4; ++nt)
      bv[nt] = *(const bf16x8*)(W3t + (size_t)(nt * 16 + l15) * 128 + ko);
  };
  auto mfma8 = [&](const bf16x8 (&av)[2], const bf16x8 (&bv)[4]) {
#pragma unroll
    for (int mt = 0; mt < 2; ++mt)
#pragma unroll
      for (int nt = 0; nt < 4; ++nt)
        acc3[mt][nt] =
            __builtin_amdgcn_mfma_f32_16x16x32_bf16(av[mt], bv[nt], acc3[mt][nt], 0, 0, 0);
  };
  ld3(0, a3A, bA);
  ld3(32, a3B, bB);
  mfma8(a3A, bA);
  ld3(64, a3A, bA);
  mfma8(a3B, bB);
  ld3(96, a3B, bB);
  mfma8(a3A, bA);
  mfma8(a3B, bB);

  float bcol[4];
#pragma unroll
  for (int nt = 0; nt < 4; ++nt) bcol[nt] = b3[nt * 16 + l15];

#pragma unroll
  for (int mt = 0; mt < 2; ++mt) {
#pragma unroll
    for (int i = 0; i < 4; ++i) {
      int r = rowbase + wave * 32 + mt * 16 + quad * 4 + i;
      float v0 = acc3[mt][0][i] + bcol[0];
      float v1 = acc3[mt][1][i] + bcol[1];
      float v2 = acc3[mt][2][i] + bcol[2];
      float v3 = acc3[mt][3][i] + bcol[3];
      float m = fmaxf(fmaxf(v0, v1), fmaxf(v2, v3));
#pragma unroll
      for (int off = 8; off > 0; off >>= 1) m = fmaxf(m, __shfl_xor(m, off, 16));
      float s = __expf(v0 - m) + __expf(v1 - m) + __expf(v2 - m) + __expf(v3 - m);
#pragma unroll
      for (int off = 8; off > 0; off >>= 1) s += __shfl_xor(s, off, 16);
      float ls = m + __logf(s);
      if (r < M) {
        if (isbf) {
          bf16* op = (bf16*)out + (size_t)r * 64 + l15;
          op[0] = __float2bfloat16(v0 - ls);
          op[16] = __float2bfloat16(v1 - ls);
          op[32] = __float2bfloat16(v2 - ls);
          op[48] = __float2bfloat16(v3 - ls);
        } else {
          float* op = (float*)out + (size_t)r * 64 + l15;
          op[0] = v0 - ls;
          op[16] = v1 - ls;
          op[32] = v2 - ls;
          op[48] = v3 - ls;
        }
      }
    }
  }
}

// ---------- launch ----------

extern "C" void kernel_launch(void* const* d_in, const int* in_sizes, int n_in,
                              void* d_out, int out_size, void* d_ws, size_t ws_size,
                              hipStream_t stream) {
  const void* x = d_in[0];
  const int* ei = (const int*)d_in[1];

  const int N = in_sizes[0] / 512;
  const int E = in_sizes[1] / 2;
  const int* srcp = ei;
  const int* dstp = ei + E;

  char* ws = (char*)d_ws;
  size_t off = 0;
  auto alloc = [&](size_t bytes) {
    void* p = ws + off;
    off = (off + bytes + 255) & ~(size_t)255;
    return p;
  };
  int*    flag    = (int*)alloc(4);
  int*    deg     = (int*)alloc((size_t)N * 4);
  int*    cursor  = (int*)alloc((size_t)N * 4);
  int*    row_ptr = (int*)alloc((size_t)(N + 1) * 4);
  int*    col     = (int*)alloc((size_t)E * 4);
  float*  dinv    = (float*)alloc((size_t)N * 4);
  int*    bsum    = (int*)alloc(1024 * 4);
  __bf16* W0t     = (__bf16*)alloc((size_t)512 * 128 * 2);
  __bf16* W1t     = (__bf16*)alloc((size_t)128 * 128 * 2);
  __bf16* W2t     = (__bf16*)alloc((size_t)128 * 128 * 2);
  __bf16* fc1t    = (__bf16*)alloc((size_t)128 * 128 * 2);
  __bf16* fc2t    = (__bf16*)alloc((size_t)128 * 128 * 2);
  __bf16* fc3t    = (__bf16*)alloc((size_t)64 * 128 * 2);
  float*  b0f     = (float*)alloc(128 * 4);
  float*  b1f     = (float*)alloc(128 * 4);
  float*  b2f     = (float*)alloc(128 * 4);
  float*  fc1bf   = (float*)alloc(128 * 4);
  float*  fc2bf   = (float*)alloc(128 * 4);
  float*  fc3bf   = (float*)alloc(64 * 4);
  bf16*   gbuf    = (bf16*)alloc((size_t)N * 128 * 2);
  bf16*   ybuf    = (bf16*)alloc((size_t)N * 128 * 2);

  const int tb = 256;

  detect_kernel<<<1, 64, 0, stream>>>((const unsigned short*)x, flag);

  CvtAll ca;
  ca.d[0]  = {d_in[2],  W0t,   512 * 128, 512, 128, 1};
  ca.d[1]  = {d_in[4],  W1t,   128 * 128, 128, 128, 1};
  ca.d[2]  = {d_in[6],  W2t,   128 * 128, 128, 128, 1};
  ca.d[3]  = {d_in[8],  fc1t,  128 * 128, 128, 128, 1};
  ca.d[4]  = {d_in[10], fc2t,  128 * 128, 128, 128, 1};
  ca.d[5]  = {d_in[3],  b0f,   128, 0, 0, 0};
  ca.d[6]  = {d_in[5],  b1f,   128, 0, 0, 0};
  ca.d[7]  = {d_in[7],  b2f,   128, 0, 0, 0};
  ca.d[8]  = {d_in[9],  fc1bf, 128, 0, 0, 0};
  ca.d[9]  = {d_in[11], fc2bf, 128, 0, 0, 0};
  ca.d[10] = {d_in[12], fc3t,  128 * 64, 128, 64, 1};
  ca.d[11] = {d_in[13], fc3bf, 64, 0, 0, 0};
  convert_all_kernel<<<dim3(64, 12), 256, 0, stream>>>(ca, flag);

  hipMemsetAsync(deg, 0, (size_t)N * 4, stream);
  hipMemsetAsync(cursor, 0, (size_t)N * 4, stream);

  count_kernel<<<(E + tb - 1) / tb, tb, 0, stream>>>(dstp, deg, E);
  dinv_kernel<<<(N + tb - 1) / tb, tb, 0, stream>>>(deg, dinv, N);
  int nb = (N + 1023) / 1024;
  scan_block_kernel<<<nb, 1024, 0, stream>>>(deg, row_ptr, bsum, N);
  scan_sums_kernel<<<1, 1024, 0, stream>>>(bsum, nb, row_ptr, N);
  scan_add_kernel<<<(N + tb - 1) / tb, tb, 0, stream>>>(row_ptr, bsum, N);
  fill_kernel<<<(E + tb - 1) / tb, tb, 0, stream>>>(srcp, dstp, row_ptr, cursor, col, E);

  int gemm_blocks = (N + 127) / 128;
  int gat_blocks = (N + 3) / 4;

  // conv0 (K=512: LDS-staged pipeline)
  gemm_mfma_kernel<512, 1><<<gemm_blocks, 256, 0, stream>>>(x, W0t, b0f, gbuf, N, dinv, 0, flag);
  gather_kernel<<<gat_blocks, 256, 0, stream>>>(gbuf, row_ptr, col, dinv, ybuf, N);
  // conv1 (K=128: reg-dbuf)
  gemm_mfma_reg_kernel<128, 0><<<gemm_blocks, 256, 0, stream>>>(ybuf, W1t, b1f, gbuf, N, dinv, 0, flag);
  gather_kernel<<<gat_blocks, 256, 0, stream>>>(gbuf, row_ptr, col, dinv, ybuf, N);
  // conv2 (K=128: reg-dbuf)
  gemm_mfma_reg_kernel<128, 0><<<gemm_blocks, 256, 0, stream>>>(ybuf, W2t, b2f, gbuf, N, dinv, 0, flag);
  gather_kernel<<<gat_blocks, 256, 0, stream>>>(gbuf, row_ptr, col, dinv, ybuf, N);
  // fused fc1+fc2+fc3+log_softmax
  fc_chain_kernel<<<gemm_blocks, 256, 0, stream>>>(ybuf, fc1t, fc1bf, fc2t, fc2bf,
                                                   fc3t, fc3bf, d_out, N, flag);
}

// Round 7
// 810.220 us; speedup vs baseline: 1.0812x; 1.0812x over previous
//
#include <hip/hip_runtime.h>
#include <hip/hip_bf16.h>
#include <cstdint>

typedef __hip_bfloat16 bf16;
typedef __hip_bfloat162 bf162;
typedef __bf16 bf16x8 __attribute__((ext_vector_type(8)));
typedef float f32x4 __attribute__((ext_vector_type(4)));

// ---------- dtype detection ----------
__global__ void detect_kernel(const unsigned short* __restrict__ xr, int* __restrict__ flag) {
  if (threadIdx.x == 0 && blockIdx.x == 0) {
    int pass = 0;
    for (int i = 0; i < 64; ++i) {
      unsigned short h = xr[2 * i];
      int e = (h >> 7) & 0xFF;
      if (e >= 110 && e <= 140) pass++;
    }
    *flag = (pass >= 32) ? 1 : 0;
  }
}

// ---------- batched weight conversion: 12 tensors in one launch ----------
struct CvtDesc {
  const void* src;
  void* dst;
  int n, fi, fo, mode;  // mode 1: transpose [fi][fo] -> bf16 [fo][fi]; mode 0: flat fp32
};
struct CvtAll { CvtDesc d[12]; };

__global__ void convert_all_kernel(CvtAll all, const int* __restrict__ flag) {
  CvtDesc dd = all.d[blockIdx.y];
  int isbf = *flag;
  for (int i = blockIdx.x * blockDim.x + threadIdx.x; i < dd.n; i += gridDim.x * blockDim.x) {
    float v = isbf ? __bfloat162float(((const bf16*)dd.src)[i]) : ((const float*)dd.src)[i];
    if (dd.mode) {
      int k = i / dd.fo, nn = i - k * dd.fo;
      ((__bf16*)dd.dst)[(size_t)nn * dd.fi + k] = (__bf16)v;
    } else {
      ((float*)dd.dst)[i] = v;
    }
  }
}

// ---------- graph preprocessing ----------

__global__ void count_kernel(const int* __restrict__ dst, int* __restrict__ deg, int E) {
  int i = blockIdx.x * blockDim.x + threadIdx.x;
  if (i < E) atomicAdd(&deg[dst[i]], 1);
}

// scan_block also emits dinv = rsqrt(deg+1) (it reads deg anyway; saves a launch)
__global__ void scan_block_kernel(const int* __restrict__ counts, int* __restrict__ excl,
                                  int* __restrict__ bsum, float* __restrict__ dinv, int n) {
  __shared__ int sd[1024];
  int t = threadIdx.x;
  int i = blockIdx.x * 1024 + t;
  int v = (i < n) ? counts[i] : 0;
  if (i < n) dinv[i] = rsqrtf((float)(v + 1));  // +1 self-loop
  sd[t] = v;
  __syncthreads();
  for (int off = 1; off < 1024; off <<= 1) {
    int x = (t >= off) ? sd[t - off] : 0;
    __syncthreads();
    sd[t] += x;
    __syncthreads();
  }
  if (i < n) excl[i] = sd[t] - v;
  if (t == 1023) bsum[blockIdx.x] = sd[1023];
}

__global__ void scan_sums_kernel(int* __restrict__ bsum, int nb, int* __restrict__ row_ptr, int n) {
  __shared__ int sd[1024];
  int t = threadIdx.x;
  int v = (t < nb) ? bsum[t] : 0;
  sd[t] = v;
  __syncthreads();
  for (int off = 1; off < 1024; off <<= 1) {
    int x = (t >= off) ? sd[t - off] : 0;
    __syncthreads();
    sd[t] += x;
    __syncthreads();
  }
  if (t < nb) bsum[t] = sd[t] - v;
  if (t == 1023) row_ptr[n] = sd[1023];
}

__global__ void scan_add_kernel(int* __restrict__ excl, const int* __restrict__ bsum, int n) {
  int i = blockIdx.x * blockDim.x + threadIdx.x;
  if (i < n) excl[i] += bsum[i >> 10];
}

// fill claims slots by counting deg back down (deg is dead after scan+dinv):
// k = atomicSub(deg[d])-1 in [0, deg-1]. Drops the cursor buffer + its memset.
__global__ void fill_kernel(const int* __restrict__ src, const int* __restrict__ dst,
                            const int* __restrict__ row_ptr, int* __restrict__ deg,
                            int* __restrict__ col, int E) {
  int i = blockIdx.x * blockDim.x + threadIdx.x;
  if (i < E) {
    int d = dst[i];
    int k = atomicSub(&deg[d], 1) - 1;
    col[row_ptr[d] + k] = src[i];
  }
}

// ---------- async global->LDS helper (16B, literal size per guide) ----------
__device__ __forceinline__ void gload_lds16(const void* g, void* l) {
  __builtin_amdgcn_global_load_lds(
      (const __attribute__((address_space(1))) void*)g,
      (__attribute__((address_space(3))) void*)l, 16, 0, 0);
}

// ---------- MFMA GEMM, m97-style LDS-staged 2-phase pipeline ----------
// C[M,128] = A[M,K] @ Bt^T + bias; Bt: [128][K] bf16. Used for ALL convs:
// round-5 A/B showed the reg-dbuf K=128 variant was WORSE (reverting it was
// part of the +68us regression) -> LDS staging stays for K=128 too.
// BK=64 double-buffered staging via global_load_lds; XOR swizzle slot^(row&7)
// as pre-swizzled GLOBAL source + swizzled read addr, LDS dest linear
// (rule #21). Wave: 64x64 quadrant via 4x4 of 16x16x32 MFMA; C/D layout
// col=lane&15, row=quad*4+reg [m89/m91]. LDS 64KB -> 2 blocks/CU.

template <int K, int ADUAL>
__global__ __launch_bounds__(256) void gemm_mfma_kernel(
    const void* __restrict__ Ain, const __bf16* __restrict__ Bt,
    const float* __restrict__ bias, bf16* __restrict__ C,
    int M, const float* __restrict__ rowscale, int do_relu,
    const int* __restrict__ flag) {
  constexpr int BK = 64;        // K-elems per tile (128B rows in LDS)
  constexpr int NT = K / BK;
  __shared__ __align__(16) __bf16 As[2][128 * BK];  // 16KB per buffer
  __shared__ __align__(16) __bf16 Bs[2][128 * BK];

  const int abf = ADUAL ? flag[0] : 1;  // 1 => A is bf16
  int t = threadIdx.x;
  int wave = t >> 6, lane = t & 63;
  int l15 = lane & 15, quad = lane >> 4;
  int wm = wave >> 1, wn = wave & 1;
  int rowbase = blockIdx.x * 128;
  const __bf16* Ab = (const __bf16*)Ain;
  const float* Af = (const float*)Ain;

  // staging decomposition: thread t covers LDS row srow(+32 per inst), slot sslot
  int srow = t >> 3;       // 0..31
  int sslot = t & 7;       // 16B slot within 128B row
  int xslot = sslot ^ (srow & 7);  // pre-swizzled source slot

  int sArow[4];  // clamped global A rows for the 4 staging insts
#pragma unroll
  for (int i = 0; i < 4; ++i) {
    int r = rowbase + i * 32 + srow;
    sArow[i] = (r < M) ? r : (M - 1);  // dup loads harmless; masked at store
  }

  f32x4 acc[4][4];
#pragma unroll
  for (int mt = 0; mt < 4; ++mt)
#pragma unroll
    for (int nt = 0; nt < 4; ++nt) acc[mt][nt] = (f32x4){0.f, 0.f, 0.f, 0.f};

  auto stage = [&](int kt, int buf) {
    int kbase = kt * BK + xslot * 8;  // element offset incl. swizzled slot
    if (abf) {
#pragma unroll
      for (int i = 0; i < 4; ++i)
        gload_lds16(Ab + (size_t)sArow[i] * K + kbase, &As[buf][t * 8 + i * 2048]);
    } else {
#pragma unroll
      for (int i = 0; i < 4; ++i) {
        const float* p = Af + (size_t)sArow[i] * K + kbase;
        bf16x8 v;
#pragma unroll
        for (int j = 0; j < 8; ++j) v[j] = (__bf16)p[j];
        *(bf16x8*)&As[buf][t * 8 + i * 2048] = v;
      }
    }
#pragma unroll
    for (int i = 0; i < 4; ++i)
      gload_lds16(Bt + (size_t)(i * 32 + srow) * K + kbase, &Bs[buf][t * 8 + i * 2048]);
  };

  auto compute = [&](int buf) {
#pragma unroll
    for (int c = 0; c < 2; ++c) {  // two K=32 chunks per BK=64 tile
      bf16x8 av[4], bv[4];
#pragma unroll
      for (int mt = 0; mt < 4; ++mt) {
        int row = wm * 64 + mt * 16 + l15;
        int slot = (c * 4 + quad) ^ (row & 7);
        av[mt] = *(const bf16x8*)&As[buf][row * BK + slot * 8];
      }
#pragma unroll
      for (int nt = 0; nt < 4; ++nt) {
        int row = wn * 64 + nt * 16 + l15;
        int slot = (c * 4 + quad) ^ (row & 7);
        bv[nt] = *(const bf16x8*)&Bs[buf][row * BK + slot * 8];
      }
#pragma unroll
      for (int mt = 0; mt < 4; ++mt)
#pragma unroll
        for (int nt = 0; nt < 4; ++nt)
          acc[mt][nt] =
              __builtin_amdgcn_mfma_f32_16x16x32_bf16(av[mt], bv[nt], acc[mt][nt], 0, 0, 0);
    }
  };

  stage(0, 0);
  __syncthreads();  // drains vmcnt(0): tile 0 resident
#pragma unroll
  for (int kt = 0; kt < NT; ++kt) {
    int cur = kt & 1;
    if (kt + 1 < NT) stage(kt + 1, cur ^ 1);  // async DMA flies under compute
    compute(cur);
    __syncthreads();  // vmcnt(0)+barrier: next tile ready, cur reusable
  }

#pragma unroll
  for (int mt = 0; mt < 4; ++mt) {
    int r0 = rowbase + wm * 64 + mt * 16 + quad * 4;
#pragma unroll
    for (int nt = 0; nt < 4; ++nt) {
      int c = wn * 64 + nt * 16 + l15;
      float bs = bias[c];
#pragma unroll
      for (int i = 0; i < 4; ++i) {
        int r = r0 + i;
        if (r < M) {
          float v = acc[mt][nt][i] + bs;
          if (rowscale) v *= rowscale[r];
          if (do_relu) v = fmaxf(v, 0.f);
          C[(size_t)r * 128 + c] = __float2bfloat16(v);
        }
      }
    }
  }
}

// ---------- gather: y[d] = relu(dinv[d]*(g[d] + sum_{s in CSR[d]} g[s])) ----------
// Latency-bound random 256B row reads (L3-resident g). 8-wide batches with
// NEXT batch's col indices prefetched while current rows are in flight,
// breaking the serial col->row dependent chain. Width stays 8 (round-5
// lesson: 16-wide crossed the 128-VGPR occupancy step and regressed; this
// version is ~55 VGPR, under the 64 boundary).

__global__ __launch_bounds__(256) void gather_kernel(
    const bf16* __restrict__ g, const int* __restrict__ row_ptr, const int* __restrict__ col,
    const float* __restrict__ dinv, bf16* __restrict__ y, int n) {
  int wave = threadIdx.x >> 6;
  int lane = threadIdx.x & 63;
  int node = blockIdx.x * 4 + wave;
  if (node >= n) return;
  const bf162* gp = (const bf162*)g;
  bf162 sv = gp[(size_t)node * 64 + lane];
  float ax = __bfloat162float(sv.x), ay = __bfloat162float(sv.y);
  float bx = 0.f, by = 0.f;
  int beg = row_ptr[node], end = row_ptr[node + 1];

  if (beg < end) {
    int sc[8], sn[8];
    float mc[8], mn[8];
#pragma unroll
    for (int j = 0; j < 8; ++j) {
      int ee = beg + j;
      bool ok = ee < end;
      sc[j] = col[ok ? ee : beg];
      mc[j] = ok ? 1.f : 0.f;
    }
    for (int e = beg; e < end; e += 8) {
      // issue current batch's 8 row loads
      bf162 v[8];
#pragma unroll
      for (int j = 0; j < 8; ++j) v[j] = gp[(size_t)sc[j] * 64 + lane];
      // prefetch next batch's col indices while rows are in flight
      int e2 = e + 8;
      bool more = e2 < end;
      if (more) {
#pragma unroll
        for (int j = 0; j < 8; ++j) {
          int ee = e2 + j;
          bool ok = ee < end;
          sn[j] = col[ok ? ee : beg];
          mn[j] = ok ? 1.f : 0.f;
        }
      }
      // accumulate (4 independent fma chains)
#pragma unroll
      for (int j = 0; j < 8; j += 2) {
        ax = fmaf(mc[j], __bfloat162float(v[j].x), ax);
        ay = fmaf(mc[j], __bfloat162float(v[j].y), ay);
        bx = fmaf(mc[j + 1], __bfloat162float(v[j + 1].x), bx);
        by = fmaf(mc[j + 1], __bfloat162float(v[j + 1].y), by);
      }
      if (more) {
#pragma unroll
        for (int j = 0; j < 8; ++j) {
          sc[j] = sn[j];
          mc[j] = mn[j];
        }
      }
    }
  }
  float dv = dinv[node];
  float ox = fmaxf((ax + bx) * dv, 0.f);
  float oy = fmaxf((ay + by) * dv, 0.f);
  bf162 o;
  o.x = __float2bfloat16(ox);
  o.y = __float2bfloat16(oy);
  ((bf162*)y)[(size_t)node * 64 + lane] = o;
}

// ---------- fused FC chain: out = log_softmax(relu(relu(y@W1+b1)@W2+b2)@W3+b3) ----------
// All three FC layers are row-local -> fuse per 128-row block. LDS h-tiles
// padded to 136 elems/row (272B = 17*16B): 16B-aligned ds_read_b128,
// row-to-row bank advance 4 -> ~2-way residual aliasing (free, m136).
// 69.6 KB LDS -> 2 blocks/CU.

__global__ __launch_bounds__(256) void fc_chain_kernel(
    const bf16* __restrict__ yin, const __bf16* __restrict__ W1t,
    const float* __restrict__ b1, const __bf16* __restrict__ W2t,
    const float* __restrict__ b2, const __bf16* __restrict__ W3t,
    const float* __restrict__ b3, void* __restrict__ out, int M,
    const int* __restrict__ flag) {
  constexpr int LDH = 136;  // padded row stride in elems
  __shared__ __align__(16) __bf16 h1[128 * LDH];
  __shared__ __align__(16) __bf16 h2[128 * LDH];
  const int isbf = flag[0];
  int t = threadIdx.x;
  int wave = t >> 6, lane = t & 63;
  int l15 = lane & 15, quad = lane >> 4;
  int wm = wave >> 1, wn = wave & 1;
  int rowbase = blockIdx.x * 128;

  f32x4 acc[4][4];
  bf16x8 aA[4], bA[4], aB[4], bB[4];

  auto zacc = [&]() {
#pragma unroll
    for (int mt = 0; mt < 4; ++mt)
#pragma unroll
      for (int nt = 0; nt < 4; ++nt) acc[mt][nt] = (f32x4){0.f, 0.f, 0.f, 0.f};
  };
  auto mfma16 = [&](const bf16x8 (&av)[4], const bf16x8 (&bv)[4]) {
#pragma unroll
    for (int mt = 0; mt < 4; ++mt)
#pragma unroll
      for (int nt = 0; nt < 4; ++nt)
        acc[mt][nt] =
            __builtin_amdgcn_mfma_f32_16x16x32_bf16(av[mt], bv[nt], acc[mt][nt], 0, 0, 0);
  };

  // ---- phase 1: h1 = relu(yin @ W1t^T + b1), A from global ----
  int arow[4];
#pragma unroll
  for (int mt = 0; mt < 4; ++mt) {
    int r = rowbase + wm * 64 + mt * 16 + l15;
    arow[mt] = (r < M) ? r : (M - 1);  // clamp; dup rows never stored to out
  }
  auto ld1 = [&](int kc, bf16x8 (&av)[4], bf16x8 (&bv)[4]) {
    int ko = kc + quad * 8;
#pragma unroll
    for (int mt = 0; mt < 4; ++mt)
      av[mt] = *(const bf16x8*)(yin + (size_t)arow[mt] * 128 + ko);
#pragma unroll
    for (int nt = 0; nt < 4; ++nt)
      bv[nt] = *(const bf16x8*)(W1t + (size_t)(wn * 64 + nt * 16 + l15) * 128 + ko);
  };
  zacc();
  ld1(0, aA, bA);
  ld1(32, aB, bB);
  mfma16(aA, bA);
  ld1(64, aA, bA);
  mfma16(aB, bB);
  ld1(96, aB, bB);
  mfma16(aA, bA);
  mfma16(aB, bB);
#pragma unroll
  for (int mt = 0; mt < 4; ++mt) {
    int rl0 = wm * 64 + mt * 16 + quad * 4;
#pragma unroll
    for (int nt = 0; nt < 4; ++nt) {
      int c = wn * 64 + nt * 16 + l15;
      float bs = b1[c];
#pragma unroll
      for (int i = 0; i < 4; ++i)
        h1[(rl0 + i) * LDH + c] = (__bf16)fmaxf(acc[mt][nt][i] + bs, 0.f);
    }
  }
  __syncthreads();

  // ---- phase 2: h2 = relu(h1 @ W2t^T + b2), A from LDS ----
  auto ld2 = [&](int kc, bf16x8 (&av)[4], bf16x8 (&bv)[4]) {
    int ko = kc + quad * 8;
#pragma unroll
    for (int mt = 0; mt < 4; ++mt)
      av[mt] = *(const bf16x8*)&h1[(wm * 64 + mt * 16 + l15) * LDH + ko];
#pragma unroll
    for (int nt = 0; nt < 4; ++nt)
      bv[nt] = *(const bf16x8*)(W2t + (size_t)(wn * 64 + nt * 16 + l15) * 128 + ko);
  };
  zacc();
  ld2(0, aA, bA);
  ld2(32, aB, bB);
  mfma16(aA, bA);
  ld2(64, aA, bA);
  mfma16(aB, bB);
  ld2(96, aB, bB);
  mfma16(aA, bA);
  mfma16(aB, bB);
#pragma unroll
  for (int mt = 0; mt < 4; ++mt) {
    int rl0 = wm * 64 + mt * 16 + quad * 4;
#pragma unroll
    for (int nt = 0; nt < 4; ++nt) {
      int c = wn * 64 + nt * 16 + l15;
      float bs = b2[c];
#pragma unroll
      for (int i = 0; i < 4; ++i)
        h2[(rl0 + i) * LDH + c] = (__bf16)fmaxf(acc[mt][nt][i] + bs, 0.f);
    }
  }
  __syncthreads();

  // ---- phase 3: out = log_softmax(h2 @ W3t^T + b3), wave w -> rows w*32.. ----
  f32x4 acc3[2][4];
#pragma unroll
  for (int mt = 0; mt < 2; ++mt)
#pragma unroll
    for (int nt = 0; nt < 4; ++nt) acc3[mt][nt] = (f32x4){0.f, 0.f, 0.f, 0.f};
  bf16x8 a3A[2], a3B[2];
  auto ld3 = [&](int kc, bf16x8 (&av)[2], bf16x8 (&bv)[4]) {
    int ko = kc + quad * 8;
#pragma unroll
    for (int mt = 0; mt < 2; ++mt)
      av[mt] = *(const bf16x8*)&h2[(wave * 32 + mt * 16 + l15) * LDH + ko];
#pragma unroll
    for (int nt = 0; nt < 4; ++nt)
      bv[nt] = *(const bf16x8*)(W3t + (size_t)(nt * 16 + l15) * 128 + ko);
  };
  auto mfma8 = [&](const bf16x8 (&av)[2], const bf16x8 (&bv)[4]) {
#pragma unroll
    for (int mt = 0; mt < 2; ++mt)
#pragma unroll
      for (int nt = 0; nt < 4; ++nt)
        acc3[mt][nt] =
            __builtin_amdgcn_mfma_f32_16x16x32_bf16(av[mt], bv[nt], acc3[mt][nt], 0, 0, 0);
  };
  ld3(0, a3A, bA);
  ld3(32, a3B, bB);
  mfma8(a3A, bA);
  ld3(64, a3A, bA);
  mfma8(a3B, bB);
  ld3(96, a3B, bB);
  mfma8(a3A, bA);
  mfma8(a3B, bB);

  float bcol[4];
#pragma unroll
  for (int nt = 0; nt < 4; ++nt) bcol[nt] = b3[nt * 16 + l15];

#pragma unroll
  for (int mt = 0; mt < 2; ++mt) {
#pragma unroll
    for (int i = 0; i < 4; ++i) {
      int r = rowbase + wave * 32 + mt * 16 + quad * 4 + i;
      float v0 = acc3[mt][0][i] + bcol[0];
      float v1 = acc3[mt][1][i] + bcol[1];
      float v2 = acc3[mt][2][i] + bcol[2];
      float v3 = acc3[mt][3][i] + bcol[3];
      float m = fmaxf(fmaxf(v0, v1), fmaxf(v2, v3));
#pragma unroll
      for (int off = 8; off > 0; off >>= 1) m = fmaxf(m, __shfl_xor(m, off, 16));
      float s = __expf(v0 - m) + __expf(v1 - m) + __expf(v2 - m) + __expf(v3 - m);
#pragma unroll
      for (int off = 8; off > 0; off >>= 1) s += __shfl_xor(s, off, 16);
      float ls = m + __logf(s);
      if (r < M) {
        if (isbf) {
          bf16* op = (bf16*)out + (size_t)r * 64 + l15;
          op[0] = __float2bfloat16(v0 - ls);
          op[16] = __float2bfloat16(v1 - ls);
          op[32] = __float2bfloat16(v2 - ls);
          op[48] = __float2bfloat16(v3 - ls);
        } else {
          float* op = (float*)out + (size_t)r * 64 + l15;
          op[0] = v0 - ls;
          op[16] = v1 - ls;
          op[32] = v2 - ls;
          op[48] = v3 - ls;
        }
      }
    }
  }
}

// ---------- launch ----------

extern "C" void kernel_launch(void* const* d_in, const int* in_sizes, int n_in,
                              void* d_out, int out_size, void* d_ws, size_t ws_size,
                              hipStream_t stream) {
  const void* x = d_in[0];
  const int* ei = (const int*)d_in[1];

  const int N = in_sizes[0] / 512;
  const int E = in_sizes[1] / 2;
  const int* srcp = ei;
  const int* dstp = ei + E;

  char* ws = (char*)d_ws;
  size_t off = 0;
  auto alloc = [&](size_t bytes) {
    void* p = ws + off;
    off = (off + bytes + 255) & ~(size_t)255;
    return p;
  };
  int*    flag    = (int*)alloc(4);
  int*    deg     = (int*)alloc((size_t)N * 4);
  int*    row_ptr = (int*)alloc((size_t)(N + 1) * 4);
  int*    col     = (int*)alloc((size_t)E * 4);
  float*  dinv    = (float*)alloc((size_t)N * 4);
  int*    bsum    = (int*)alloc(1024 * 4);
  __bf16* W0t     = (__bf16*)alloc((size_t)512 * 128 * 2);
  __bf16* W1t     = (__bf16*)alloc((size_t)128 * 128 * 2);
  __bf16* W2t     = (__bf16*)alloc((size_t)128 * 128 * 2);
  __bf16* fc1t    = (__bf16*)alloc((size_t)128 * 128 * 2);
  __bf16* fc2t    = (__bf16*)alloc((size_t)128 * 128 * 2);
  __bf16* fc3t    = (__bf16*)alloc((size_t)64 * 128 * 2);
  float*  b0f     = (float*)alloc(128 * 4);
  float*  b1f     = (float*)alloc(128 * 4);
  float*  b2f     = (float*)alloc(128 * 4);
  float*  fc1bf   = (float*)alloc(128 * 4);
  float*  fc2bf   = (float*)alloc(128 * 4);
  float*  fc3bf   = (float*)alloc(64 * 4);
  bf16*   gbuf    = (bf16*)alloc((size_t)N * 128 * 2);
  bf16*   ybuf    = (bf16*)alloc((size_t)N * 128 * 2);

  const int tb = 256;

  detect_kernel<<<1, 64, 0, stream>>>((const unsigned short*)x, flag);

  CvtAll ca;
  ca.d[0]  = {d_in[2],  W0t,   512 * 128, 512, 128, 1};
  ca.d[1]  = {d_in[4],  W1t,   128 * 128, 128, 128, 1};
  ca.d[2]  = {d_in[6],  W2t,   128 * 128, 128, 128, 1};
  ca.d[3]  = {d_in[8],  fc1t,  128 * 128, 128, 128, 1};
  ca.d[4]  = {d_in[10], fc2t,  128 * 128, 128, 128, 1};
  ca.d[5]  = {d_in[3],  b0f,   128, 0, 0, 0};
  ca.d[6]  = {d_in[5],  b1f,   128, 0, 0, 0};
  ca.d[7]  = {d_in[7],  b2f,   128, 0, 0, 0};
  ca.d[8]  = {d_in[9],  fc1bf, 128, 0, 0, 0};
  ca.d[9]  = {d_in[11], fc2bf, 128, 0, 0, 0};
  ca.d[10] = {d_in[12], fc3t,  128 * 64, 128, 64, 1};
  ca.d[11] = {d_in[13], fc3bf, 64, 0, 0, 0};
  convert_all_kernel<<<dim3(64, 12), 256, 0, stream>>>(ca, flag);

  hipMemsetAsync(deg, 0, (size_t)N * 4, stream);

  count_kernel<<<(E + tb - 1) / tb, tb, 0, stream>>>(dstp, deg, E);
  int nb = (N + 1023) / 1024;
  scan_block_kernel<<<nb, 1024, 0, stream>>>(deg, row_ptr, bsum, dinv, N);
  scan_sums_kernel<<<1, 1024, 0, stream>>>(bsum, nb, row_ptr, N);
  scan_add_kernel<<<(N + tb - 1) / tb, tb, 0, stream>>>(row_ptr, bsum, N);
  fill_kernel<<<(E + tb - 1) / tb, tb, 0, stream>>>(srcp, dstp, row_ptr, deg, col, E);

  int gemm_blocks = (N + 127) / 128;
  int gat_blocks = (N + 3) / 4;

  // conv0 (K=512)
  gemm_mfma_kernel<512, 1><<<gemm_blocks, 256, 0, stream>>>(x, W0t, b0f, gbuf, N, dinv, 0, flag);
  gather_kernel<<<gat_blocks, 256, 0, stream>>>(gbuf, row_ptr, col, dinv, ybuf, N);
  // conv1
  gemm_mfma_kernel<128, 0><<<gemm_blocks, 256, 0, stream>>>(ybuf, W1t, b1f, gbuf, N, dinv, 0, flag);
  gather_kernel<<<gat_blocks, 256, 0, stream>>>(gbuf, row_ptr, col, dinv, ybuf, N);
  // conv2
  gemm_mfma_kernel<128, 0><<<gemm_blocks, 256, 0, stream>>>(ybuf, W2t, b2f, gbuf, N, dinv, 0, flag);
  gather_kernel<<<gat_blocks, 256, 0, stream>>>(gbuf, row_ptr, col, dinv, ybuf, N);
  // fused fc1+fc2+fc3+log_softmax
  fc_chain_kernel<<<gemm_blocks, 256, 0, stream>>>(ybuf, fc1t, fc1bf, fc2t, fc2bf,
                                                   fc3t, fc3bf, d_out, N, flag);
}

// Round 8
// 808.292 us; speedup vs baseline: 1.0838x; 1.0024x over previous
//
#include <hip/hip_runtime.h>
#include <hip/hip_bf16.h>
#include <cstdint>

typedef __hip_bfloat16 bf16;
typedef __hip_bfloat162 bf162;
typedef __bf16 bf16x8 __attribute__((ext_vector_type(8)));
typedef float f32x4 __attribute__((ext_vector_type(4)));

// ---------- dtype detection ----------
__global__ void detect_kernel(const unsigned short* __restrict__ xr, int* __restrict__ flag) {
  if (threadIdx.x == 0 && blockIdx.x == 0) {
    int pass = 0;
    for (int i = 0; i < 64; ++i) {
      unsigned short h = xr[2 * i];
      int e = (h >> 7) & 0xFF;
      if (e >= 110 && e <= 140) pass++;
    }
    *flag = (pass >= 32) ? 1 : 0;
  }
}

// ---------- batched weight conversion: 12 tensors in one launch ----------
struct CvtDesc {
  const void* src;
  void* dst;
  int n, fi, fo, mode;  // mode 1: transpose [fi][fo] -> bf16 [fo][fi]; mode 0: flat fp32
};
struct CvtAll { CvtDesc d[12]; };

__global__ void convert_all_kernel(CvtAll all, const int* __restrict__ flag) {
  CvtDesc dd = all.d[blockIdx.y];
  int isbf = *flag;
  for (int i = blockIdx.x * blockDim.x + threadIdx.x; i < dd.n; i += gridDim.x * blockDim.x) {
    float v = isbf ? __bfloat162float(((const bf16*)dd.src)[i]) : ((const float*)dd.src)[i];
    if (dd.mode) {
      int k = i / dd.fo, nn = i - k * dd.fo;
      ((__bf16*)dd.dst)[(size_t)nn * dd.fi + k] = (__bf16)v;
    } else {
      ((float*)dd.dst)[i] = v;
    }
  }
}

// ---------- graph preprocessing ----------

__global__ void count_kernel(const int* __restrict__ dst, int* __restrict__ deg, int E) {
  int i = blockIdx.x * blockDim.x + threadIdx.x;
  if (i < E) atomicAdd(&deg[dst[i]], 1);
}

// scan_block also emits dinv = rsqrt(deg+1) (it reads deg anyway; saves a launch)
__global__ void scan_block_kernel(const int* __restrict__ counts, int* __restrict__ excl,
                                  int* __restrict__ bsum, float* __restrict__ dinv, int n) {
  __shared__ int sd[1024];
  int t = threadIdx.x;
  int i = blockIdx.x * 1024 + t;
  int v = (i < n) ? counts[i] : 0;
  if (i < n) dinv[i] = rsqrtf((float)(v + 1));  // +1 self-loop
  sd[t] = v;
  __syncthreads();
  for (int off = 1; off < 1024; off <<= 1) {
    int x = (t >= off) ? sd[t - off] : 0;
    __syncthreads();
    sd[t] += x;
    __syncthreads();
  }
  if (i < n) excl[i] = sd[t] - v;
  if (t == 1023) bsum[blockIdx.x] = sd[1023];
}

__global__ void scan_sums_kernel(int* __restrict__ bsum, int nb, int* __restrict__ row_ptr, int n) {
  __shared__ int sd[1024];
  int t = threadIdx.x;
  int v = (t < nb) ? bsum[t] : 0;
  sd[t] = v;
  __syncthreads();
  for (int off = 1; off < 1024; off <<= 1) {
    int x = (t >= off) ? sd[t - off] : 0;
    __syncthreads();
    sd[t] += x;
    __syncthreads();
  }
  if (t < nb) bsum[t] = sd[t] - v;
  if (t == 1023) row_ptr[n] = sd[1023];
}

__global__ void scan_add_kernel(int* __restrict__ excl, const int* __restrict__ bsum, int n) {
  int i = blockIdx.x * blockDim.x + threadIdx.x;
  if (i < n) excl[i] += bsum[i >> 10];
}

// fill claims slots by counting deg back down (deg is dead after scan+dinv):
// k = atomicSub(deg[d])-1 in [0, deg-1]. Drops the cursor buffer + its memset.
__global__ void fill_kernel(const int* __restrict__ src, const int* __restrict__ dst,
                            const int* __restrict__ row_ptr, int* __restrict__ deg,
                            int* __restrict__ col, int E) {
  int i = blockIdx.x * blockDim.x + threadIdx.x;
  if (i < E) {
    int d = dst[i];
    int k = atomicSub(&deg[d], 1) - 1;
    col[row_ptr[d] + k] = src[i];
  }
}

// ---------- async global->LDS helper (16B, literal size per guide) ----------
__device__ __forceinline__ void gload_lds16(const void* g, void* l) {
  __builtin_amdgcn_global_load_lds(
      (const __attribute__((address_space(1))) void*)g,
      (__attribute__((address_space(3))) void*)l, 16, 0, 0);
}

// ---------- MFMA GEMM, LDS-staged with COUNTED-vmcnt pipeline (T4) ----------
// C[M,128] = A[M,K] @ Bt^T + bias; Bt: [128][K] bf16.
// Round-7 profile: conv0 = 138us with MfmaUtil 3.5% / hbm 938 GB/s /
// Occ 18% -- IDENTICAL to the round-1 no-LDS version. Shared structural
// stall: __syncthreads() emits s_waitcnt vmcnt(0) before s_barrier, draining
// all DMA every K-step (8 serialized HBM round-trips/block, ~3 blocks/CU).
// Fix = guide T4 (m218: counted-vs-drain0 +38-73%): each wave issues exactly
// 8 gload_lds per stage; steady state keeps 16 outstanding and waits
// vmcnt(8) -- own tile-k DMAs retired, tile-k+1 stays in flight across a RAW
// s_barrier (all waves' tile-k writes landed). Second barrier after compute
// protects buf reuse at step k+2. sched_barrier(0) fences per rule #18.
// fp32-A fallback path keeps the old __syncthreads loop (stores break the
// vmcnt count; path is never taken at runtime -- FETCH shows bf16 x).
// XOR swizzle slot^(row&7) as pre-swizzled GLOBAL source + swizzled read,
// LDS dest linear (rule #21). Wave: 64x64 via 4x4 of 16x16x32 MFMA; C/D
// layout col=lane&15, row=quad*4+reg [m89/m91]. LDS 64KB -> 2 blocks/CU.

template <int K, int ADUAL>
__global__ __launch_bounds__(256) void gemm_mfma_kernel(
    const void* __restrict__ Ain, const __bf16* __restrict__ Bt,
    const float* __restrict__ bias, bf16* __restrict__ C,
    int M, const float* __restrict__ rowscale, int do_relu,
    const int* __restrict__ flag) {
  constexpr int BK = 64;        // K-elems per tile (128B rows in LDS)
  constexpr int NT = K / BK;
  __shared__ __align__(16) __bf16 As[2][128 * BK];  // 16KB per buffer
  __shared__ __align__(16) __bf16 Bs[2][128 * BK];

  const int abf = ADUAL ? flag[0] : 1;  // 1 => A is bf16
  int t = threadIdx.x;
  int wave = t >> 6, lane = t & 63;
  int l15 = lane & 15, quad = lane >> 4;
  int wm = wave >> 1, wn = wave & 1;
  int rowbase = blockIdx.x * 128;
  const __bf16* Ab = (const __bf16*)Ain;
  const float* Af = (const float*)Ain;

  // staging decomposition: thread t covers LDS row srow(+32 per inst), slot sslot
  int srow = t >> 3;       // 0..31
  int sslot = t & 7;       // 16B slot within 128B row
  int xslot = sslot ^ (srow & 7);  // pre-swizzled source slot

  int sArow[4];  // clamped global A rows for the 4 staging insts
#pragma unroll
  for (int i = 0; i < 4; ++i) {
    int r = rowbase + i * 32 + srow;
    sArow[i] = (r < M) ? r : (M - 1);  // dup loads harmless; masked at store
  }

  f32x4 acc[4][4];
#pragma unroll
  for (int mt = 0; mt < 4; ++mt)
#pragma unroll
    for (int nt = 0; nt < 4; ++nt) acc[mt][nt] = (f32x4){0.f, 0.f, 0.f, 0.f};

  auto stage = [&](int kt, int buf) {
    int kbase = kt * BK + xslot * 8;  // element offset incl. swizzled slot
    if (abf) {
#pragma unroll
      for (int i = 0; i < 4; ++i)
        gload_lds16(Ab + (size_t)sArow[i] * K + kbase, &As[buf][t * 8 + i * 2048]);
    } else {
#pragma unroll
      for (int i = 0; i < 4; ++i) {
        const float* p = Af + (size_t)sArow[i] * K + kbase;
        bf16x8 v;
#pragma unroll
        for (int j = 0; j < 8; ++j) v[j] = (__bf16)p[j];
        *(bf16x8*)&As[buf][t * 8 + i * 2048] = v;
      }
    }
#pragma unroll
    for (int i = 0; i < 4; ++i)
      gload_lds16(Bt + (size_t)(i * 32 + srow) * K + kbase, &Bs[buf][t * 8 + i * 2048]);
  };

  auto compute = [&](int buf) {
#pragma unroll
    for (int c = 0; c < 2; ++c) {  // two K=32 chunks per BK=64 tile
      bf16x8 av[4], bv[4];
#pragma unroll
      for (int mt = 0; mt < 4; ++mt) {
        int row = wm * 64 + mt * 16 + l15;
        int slot = (c * 4 + quad) ^ (row & 7);
        av[mt] = *(const bf16x8*)&As[buf][row * BK + slot * 8];
      }
#pragma unroll
      for (int nt = 0; nt < 4; ++nt) {
        int row = wn * 64 + nt * 16 + l15;
        int slot = (c * 4 + quad) ^ (row & 7);
        bv[nt] = *(const bf16x8*)&Bs[buf][row * BK + slot * 8];
      }
#pragma unroll
      for (int mt = 0; mt < 4; ++mt)
#pragma unroll
        for (int nt = 0; nt < 4; ++nt)
          acc[mt][nt] =
              __builtin_amdgcn_mfma_f32_16x16x32_bf16(av[mt], bv[nt], acc[mt][nt], 0, 0, 0);
    }
  };

  stage(0, 0);
  if (abf) {
    // T4 counted-vmcnt pipeline: per-wave 8 DMAs/stage; steady state 16
    // outstanding; vmcnt(8) retires exactly tile-k's; next tile stays in
    // flight across the raw barrier.
#pragma unroll
    for (int kt = 0; kt < NT; ++kt) {
      int cur = kt & 1;
      if (kt + 1 < NT) {
        stage(kt + 1, cur ^ 1);
        asm volatile("s_waitcnt vmcnt(8)" ::: "memory");
      } else {
        asm volatile("s_waitcnt vmcnt(0)" ::: "memory");
      }
      __builtin_amdgcn_sched_barrier(0);
      __builtin_amdgcn_s_barrier();     // all waves' tile-kt writes landed
      __builtin_amdgcn_sched_barrier(0);
      compute(cur);
      __builtin_amdgcn_sched_barrier(0);
      __builtin_amdgcn_s_barrier();     // all reads of buf done before kt+2 overwrites
    }
  } else {
    // fallback (fp32 A): plain stores break the vmcnt count -> old structure
    __syncthreads();
#pragma unroll
    for (int kt = 0; kt < NT; ++kt) {
      int cur = kt & 1;
      if (kt + 1 < NT) stage(kt + 1, cur ^ 1);
      compute(cur);
      __syncthreads();
    }
  }

#pragma unroll
  for (int mt = 0; mt < 4; ++mt) {
    int r0 = rowbase + wm * 64 + mt * 16 + quad * 4;
#pragma unroll
    for (int nt = 0; nt < 4; ++nt) {
      int c = wn * 64 + nt * 16 + l15;
      float bs = bias[c];
#pragma unroll
      for (int i = 0; i < 4; ++i) {
        int r = r0 + i;
        if (r < M) {
          float v = acc[mt][nt][i] + bs;
          if (rowscale) v *= rowscale[r];
          if (do_relu) v = fmaxf(v, 0.f);
          C[(size_t)r * 128 + c] = __float2bfloat16(v);
        }
      }
    }
  }
}

// ---------- gather: y[d] = relu(dinv[d]*(g[d] + sum_{s in CSR[d]} g[s])) ----------
// 8-wide batches with next-batch col prefetch. Round-7 result: prefetch was
// neutral -> gather is fabric/BW-bound for random 256B granules, not
// chain-bound. Left as-is (best measured variant).

__global__ __launch_bounds__(256) void gather_kernel(
    const bf16* __restrict__ g, const int* __restrict__ row_ptr, const int* __restrict__ col,
    const float* __restrict__ dinv, bf16* __restrict__ y, int n) {
  int wave = threadIdx.x >> 6;
  int lane = threadIdx.x & 63;
  int node = blockIdx.x * 4 + wave;
  if (node >= n) return;
  const bf162* gp = (const bf162*)g;
  bf162 sv = gp[(size_t)node * 64 + lane];
  float ax = __bfloat162float(sv.x), ay = __bfloat162float(sv.y);
  float bx = 0.f, by = 0.f;
  int beg = row_ptr[node], end = row_ptr[node + 1];

  if (beg < end) {
    int sc[8], sn[8];
    float mc[8], mn[8];
#pragma unroll
    for (int j = 0; j < 8; ++j) {
      int ee = beg + j;
      bool ok = ee < end;
      sc[j] = col[ok ? ee : beg];
      mc[j] = ok ? 1.f : 0.f;
    }
    for (int e = beg; e < end; e += 8) {
      bf162 v[8];
#pragma unroll
      for (int j = 0; j < 8; ++j) v[j] = gp[(size_t)sc[j] * 64 + lane];
      int e2 = e + 8;
      bool more = e2 < end;
      if (more) {
#pragma unroll
        for (int j = 0; j < 8; ++j) {
          int ee = e2 + j;
          bool ok = ee < end;
          sn[j] = col[ok ? ee : beg];
          mn[j] = ok ? 1.f : 0.f;
        }
      }
#pragma unroll
      for (int j = 0; j < 8; j += 2) {
        ax = fmaf(mc[j], __bfloat162float(v[j].x), ax);
        ay = fmaf(mc[j], __bfloat162float(v[j].y), ay);
        bx = fmaf(mc[j + 1], __bfloat162float(v[j + 1].x), bx);
        by = fmaf(mc[j + 1], __bfloat162float(v[j + 1].y), by);
      }
      if (more) {
#pragma unroll
        for (int j = 0; j < 8; ++j) {
          sc[j] = sn[j];
          mc[j] = mn[j];
        }
      }
    }
  }
  float dv = dinv[node];
  float ox = fmaxf((ax + bx) * dv, 0.f);
  float oy = fmaxf((ay + by) * dv, 0.f);
  bf162 o;
  o.x = __float2bfloat16(ox);
  o.y = __float2bfloat16(oy);
  ((bf162*)y)[(size_t)node * 64 + lane] = o;
}

// ---------- fused FC chain: out = log_softmax(relu(relu(y@W1+b1)@W2+b2)@W3+b3) ----------
// All three FC layers are row-local -> fuse per 128-row block. LDS h-tiles
// padded to 136 elems/row (272B = 17*16B): 16B-aligned ds_read_b128,
// row-to-row bank advance 4 -> ~2-way residual aliasing (free, m136).
// 69.6 KB LDS -> 2 blocks/CU.

__global__ __launch_bounds__(256) void fc_chain_kernel(
    const bf16* __restrict__ yin, const __bf16* __restrict__ W1t,
    const float* __restrict__ b1, const __bf16* __restrict__ W2t,
    const float* __restrict__ b2, const __bf16* __restrict__ W3t,
    const float* __restrict__ b3, void* __restrict__ out, int M,
    const int* __restrict__ flag) {
  constexpr int LDH = 136;  // padded row stride in elems
  __shared__ __align__(16) __bf16 h1[128 * LDH];
  __shared__ __align__(16) __bf16 h2[128 * LDH];
  const int isbf = flag[0];
  int t = threadIdx.x;
  int wave = t >> 6, lane = t & 63;
  int l15 = lane & 15, quad = lane >> 4;
  int wm = wave >> 1, wn = wave & 1;
  int rowbase = blockIdx.x * 128;

  f32x4 acc[4][4];
  bf16x8 aA[4], bA[4], aB[4], bB[4];

  auto zacc = [&]() {
#pragma unroll
    for (int mt = 0; mt < 4; ++mt)
#pragma unroll
      for (int nt = 0; nt < 4; ++nt) acc[mt][nt] = (f32x4){0.f, 0.f, 0.f, 0.f};
  };
  auto mfma16 = [&](const bf16x8 (&av)[4], const bf16x8 (&bv)[4]) {
#pragma unroll
    for (int mt = 0; mt < 4; ++mt)
#pragma unroll
      for (int nt = 0; nt < 4; ++nt)
        acc[mt][nt] =
            __builtin_amdgcn_mfma_f32_16x16x32_bf16(av[mt], bv[nt], acc[mt][nt], 0, 0, 0);
  };

  // ---- phase 1: h1 = relu(yin @ W1t^T + b1), A from global ----
  int arow[4];
#pragma unroll
  for (int mt = 0; mt < 4; ++mt) {
    int r = rowbase + wm * 64 + mt * 16 + l15;
    arow[mt] = (r < M) ? r : (M - 1);  // clamp; dup rows never stored to out
  }
  auto ld1 = [&](int kc, bf16x8 (&av)[4], bf16x8 (&bv)[4]) {
    int ko = kc + quad * 8;
#pragma unroll
    for (int mt = 0; mt < 4; ++mt)
      av[mt] = *(const bf16x8*)(yin + (size_t)arow[mt] * 128 + ko);
#pragma unroll
    for (int nt = 0; nt < 4; ++nt)
      bv[nt] = *(const bf16x8*)(W1t + (size_t)(wn * 64 + nt * 16 + l15) * 128 + ko);
  };
  zacc();
  ld1(0, aA, bA);
  ld1(32, aB, bB);
  mfma16(aA, bA);
  ld1(64, aA, bA);
  mfma16(aB, bB);
  ld1(96, aB, bB);
  mfma16(aA, bA);
  mfma16(aB, bB);
#pragma unroll
  for (int mt = 0; mt < 4; ++mt) {
    int rl0 = wm * 64 + mt * 16 + quad * 4;
#pragma unroll
    for (int nt = 0; nt < 4; ++nt) {
      int c = wn * 64 + nt * 16 + l15;
      float bs = b1[c];
#pragma unroll
      for (int i = 0; i < 4; ++i)
        h1[(rl0 + i) * LDH + c] = (__bf16)fmaxf(acc[mt][nt][i] + bs, 0.f);
    }
  }
  __syncthreads();

  // ---- phase 2: h2 = relu(h1 @ W2t^T + b2), A from LDS ----
  auto ld2 = [&](int kc, bf16x8 (&av)[4], bf16x8 (&bv)[4]) {
    int ko = kc + quad * 8;
#pragma unroll
    for (int mt = 0; mt < 4; ++mt)
      av[mt] = *(const bf16x8*)&h1[(wm * 64 + mt * 16 + l15) * LDH + ko];
#pragma unroll
    for (int nt = 0; nt < 4; ++nt)
      bv[nt] = *(const bf16x8*)(W2t + (size_t)(wn * 64 + nt * 16 + l15) * 128 + ko);
  };
  zacc();
  ld2(0, aA, bA);
  ld2(32, aB, bB);
  mfma16(aA, bA);
  ld2(64, aA, bA);
  mfma16(aB, bB);
  ld2(96, aB, bB);
  mfma16(aA, bA);
  mfma16(aB, bB);
#pragma unroll
  for (int mt = 0; mt < 4; ++mt) {
    int rl0 = wm * 64 + mt * 16 + quad * 4;
#pragma unroll
    for (int nt = 0; nt < 4; ++nt) {
      int c = wn * 64 + nt * 16 + l15;
      float bs = b2[c];
#pragma unroll
      for (int i = 0; i < 4; ++i)
        h2[(rl0 + i) * LDH + c] = (__bf16)fmaxf(acc[mt][nt][i] + bs, 0.f);
    }
  }
  __syncthreads();

  // ---- phase 3: out = log_softmax(h2 @ W3t^T + b3), wave w -> rows w*32.. ----
  f32x4 acc3[2][4];
#pragma unroll
  for (int mt = 0; mt < 2; ++mt)
#pragma unroll
    for (int nt = 0; nt < 4; ++nt) acc3[mt][nt] = (f32x4){0.f, 0.f, 0.f, 0.f};
  bf16x8 a3A[2], a3B[2];
  auto ld3 = [&](int kc, bf16x8 (&av)[2], bf16x8 (&bv)[4]) {
    int ko = kc + quad * 8;
#pragma unroll
    for (int mt = 0; mt < 2; ++mt)
      av[mt] = *(const bf16x8*)&h2[(wave * 32 + mt * 16 + l15) * LDH + ko];
#pragma unroll
    for (int nt = 0; nt < 4; ++nt)
      bv[nt] = *(const bf16x8*)(W3t + (size_t)(nt * 16 + l15) * 128 + ko);
  };
  auto mfma8 = [&](const bf16x8 (&av)[2], const bf16x8 (&bv)[4]) {
#pragma unroll
    for (int mt = 0; mt < 2; ++mt)
#pragma unroll
      for (int nt = 0; nt < 4; ++nt)
        acc3[mt][nt] =
            __builtin_amdgcn_mfma_f32_16x16x32_bf16(av[mt], bv[nt], acc3[mt][nt], 0, 0, 0);
  };
  ld3(0, a3A, bA);
  ld3(32, a3B, bB);
  mfma8(a3A, bA);
  ld3(64, a3A, bA);
  mfma8(a3B, bB);
  ld3(96, a3B, bB);
  mfma8(a3A, bA);
  mfma8(a3B, bB);

  float bcol[4];
#pragma unroll
  for (int nt = 0; nt < 4; ++nt) bcol[nt] = b3[nt * 16 + l15];

#pragma unroll
  for (int mt = 0; mt < 2; ++mt) {
#pragma unroll
    for (int i = 0; i < 4; ++i) {
      int r = rowbase + wave * 32 + mt * 16 + quad * 4 + i;
      float v0 = acc3[mt][0][i] + bcol[0];
      float v1 = acc3[mt][1][i] + bcol[1];
      float v2 = acc3[mt][2][i] + bcol[2];
      float v3 = acc3[mt][3][i] + bcol[3];
      float m = fmaxf(fmaxf(v0, v1), fmaxf(v2, v3));
#pragma unroll
      for (int off = 8; off > 0; off >>= 1) m = fmaxf(m, __shfl_xor(m, off, 16));
      float s = __expf(v0 - m) + __expf(v1 - m) + __expf(v2 - m) + __expf(v3 - m);
#pragma unroll
      for (int off = 8; off > 0; off >>= 1) s += __shfl_xor(s, off, 16);
      float ls = m + __logf(s);
      if (r < M) {
        if (isbf) {
          bf16* op = (bf16*)out + (size_t)r * 64 + l15;
          op[0] = __float2bfloat16(v0 - ls);
          op[16] = __float2bfloat16(v1 - ls);
          op[32] = __float2bfloat16(v2 - ls);
          op[48] = __float2bfloat16(v3 - ls);
        } else {
          float* op = (float*)out + (size_t)r * 64 + l15;
          op[0] = v0 - ls;
          op[16] = v1 - ls;
          op[32] = v2 - ls;
          op[48] = v3 - ls;
        }
      }
    }
  }
}

// ---------- launch ----------

extern "C" void kernel_launch(void* const* d_in, const int* in_sizes, int n_in,
                              void* d_out, int out_size, void* d_ws, size_t ws_size,
                              hipStream_t stream) {
  const void* x = d_in[0];
  const int* ei = (const int*)d_in[1];

  const int N = in_sizes[0] / 512;
  const int E = in_sizes[1] / 2;
  const int* srcp = ei;
  const int* dstp = ei + E;

  char* ws = (char*)d_ws;
  size_t off = 0;
  auto alloc = [&](size_t bytes) {
    void* p = ws + off;
    off = (off + bytes + 255) & ~(size_t)255;
    return p;
  };
  int*    flag    = (int*)alloc(4);
  int*    deg     = (int*)alloc((size_t)N * 4);
  int*    row_ptr = (int*)alloc((size_t)(N + 1) * 4);
  int*    col     = (int*)alloc((size_t)E * 4);
  float*  dinv    = (float*)alloc((size_t)N * 4);
  int*    bsum    = (int*)alloc(1024 * 4);
  __bf16* W0t     = (__bf16*)alloc((size_t)512 * 128 * 2);
  __bf16* W1t     = (__bf16*)alloc((size_t)128 * 128 * 2);
  __bf16* W2t     = (__bf16*)alloc((size_t)128 * 128 * 2);
  __bf16* fc1t    = (__bf16*)alloc((size_t)128 * 128 * 2);
  __bf16* fc2t    = (__bf16*)alloc((size_t)128 * 128 * 2);
  __bf16* fc3t    = (__bf16*)alloc((size_t)64 * 128 * 2);
  float*  b0f     = (float*)alloc(128 * 4);
  float*  b1f     = (float*)alloc(128 * 4);
  float*  b2f     = (float*)alloc(128 * 4);
  float*  fc1bf   = (float*)alloc(128 * 4);
  float*  fc2bf   = (float*)alloc(128 * 4);
  float*  fc3bf   = (float*)alloc(64 * 4);
  bf16*   gbuf    = (bf16*)alloc((size_t)N * 128 * 2);
  bf16*   ybuf    = (bf16*)alloc((size_t)N * 128 * 2);

  const int tb = 256;

  detect_kernel<<<1, 64, 0, stream>>>((const unsigned short*)x, flag);

  CvtAll ca;
  ca.d[0]  = {d_in[2],  W0t,   512 * 128, 512, 128, 1};
  ca.d[1]  = {d_in[4],  W1t,   128 * 128, 128, 128, 1};
  ca.d[2]  = {d_in[6],  W2t,   128 * 128, 128, 128, 1};
  ca.d[3]  = {d_in[8],  fc1t,  128 * 128, 128, 128, 1};
  ca.d[4]  = {d_in[10], fc2t,  128 * 128, 128, 128, 1};
  ca.d[5]  = {d_in[3],  b0f,   128, 0, 0, 0};
  ca.d[6]  = {d_in[5],  b1f,   128, 0, 0, 0};
  ca.d[7]  = {d_in[7],  b2f,   128, 0, 0, 0};
  ca.d[8]  = {d_in[9],  fc1bf, 128, 0, 0, 0};
  ca.d[9]  = {d_in[11], fc2bf, 128, 0, 0, 0};
  ca.d[10] = {d_in[12], fc3t,  128 * 64, 128, 64, 1};
  ca.d[11] = {d_in[13], fc3bf, 64, 0, 0, 0};
  convert_all_kernel<<<dim3(64, 12), 256, 0, stream>>>(ca, flag);

  hipMemsetAsync(deg, 0, (size_t)N * 4, stream);

  count_kernel<<<(E + tb - 1) / tb, tb, 0, stream>>>(dstp, deg, E);
  int nb = (N + 1023) / 1024;
  scan_block_kernel<<<nb, 1024, 0, stream>>>(deg, row_ptr, bsum, dinv, N);
  scan_sums_kernel<<<1, 1024, 0, stream>>>(bsum, nb, row_ptr, N);
  scan_add_kernel<<<(N + tb - 1) / tb, tb, 0, stream>>>(row_ptr, bsum, N);
  fill_kernel<<<(E + tb - 1) / tb, tb, 0, stream>>>(srcp, dstp, row_ptr, deg, col, E);

  int gemm_blocks = (N + 127) / 128;
  int gat_blocks = (N + 3) / 4;

  // conv0 (K=512)
  gemm_mfma_kernel<512, 1><<<gemm_blocks, 256, 0, stream>>>(x, W0t, b0f, gbuf, N, dinv, 0, flag);
  gather_kernel<<<gat_blocks, 256, 0, stream>>>(gbuf, row_ptr, col, dinv, ybuf, N);
  // conv1
  gemm_mfma_kernel<128, 0><<<gemm_blocks, 256, 0, stream>>>(ybuf, W1t, b1f, gbuf, N, dinv, 0, flag);
  gather_kernel<<<gat_blocks, 256, 0, stream>>>(gbuf, row_ptr, col, dinv, ybuf, N);
  // conv2
  gemm_mfma_kernel<128, 0><<<gemm_blocks, 256, 0, stream>>>(ybuf, W2t, b2f, gbuf, N, dinv, 0, flag);
  gather_kernel<<<gat_blocks, 256, 0, stream>>>(gbuf, row_ptr, col, dinv, ybuf, N);
  // fused fc1+fc2+fc3+log_softmax
  fc_chain_kernel<<<gemm_blocks, 256, 0, stream>>>(ybuf, fc1t, fc1bf, fc2t, fc2bf,
                                                   fc3t, fc3bf, d_out, N, flag);
}